// Round 1
// baseline (3311.145 us; speedup 1.0000x reference)
//
#include <hip/hip_runtime.h>
#include <hip/hip_bf16.h>
#include <cstdint>
#include <cstddef>

typedef unsigned short u16;
typedef __attribute__((ext_vector_type(8))) short short8;   // 8 bf16 (4 VGPRs)
typedef __attribute__((ext_vector_type(4))) float f32x4;    // 4 fp32 acc

#define L_SEQ 512
#define NB    64
#define HID_  1024
#define EMB_  512
#define DIN   1536          // HID + EMB
#define NKS   48            // DIN / 32 (K-steps of the 16x16x32 MFMA)
#define ARS   1544          // A-tile row stride in u16 (1536 + 8 pad -> granule stride 1 mod 8)

__device__ __forceinline__ u16 f2b(float f) {
    uint32_t u = __float_as_uint(f);
    u = (u + 0x7FFFu + ((u >> 16) & 1u)) >> 16;   // RNE fp32 -> bf16
    return (u16)u;
}

// ---------- P1: emb fp32 -> bf16 (32000x512) ----------
__global__ void cvt_emb_k(const float* __restrict__ src, u16* __restrict__ dst) {
    size_t i = ((size_t)blockIdx.x * blockDim.x + threadIdx.x) * 8;
    float4 a = *(const float4*)(src + i);
    float4 b = *(const float4*)(src + i + 4);
    short8 v;
    v[0] = (short)f2b(a.x); v[1] = (short)f2b(a.y);
    v[2] = (short)f2b(a.z); v[3] = (short)f2b(a.w);
    v[4] = (short)f2b(b.x); v[5] = (short)f2b(b.y);
    v[6] = (short)f2b(b.z); v[7] = (short)f2b(b.w);
    *(short8*)(dst + i) = v;
}

// ---------- P2: pack 4 gate weights (full K=1536 rows) into B-fragment order ----------
// Layout: whxp[(ug*4+gate)*48 + ks][lane][8 elems], elem e at k = ks*32 + (lane>>4)*8 + e,
// col = ug*16 + (lane&15). Same (lane,e)->k convention used for A fragments, so any
// hardware k-permutation cancels (A/B consistency is what matters).
__global__ void pack_w_k(const float* __restrict__ Wi, const float* __restrict__ Wf,
                         const float* __restrict__ Wc, const float* __restrict__ Wo,
                         u16* __restrict__ whxp) {
    int b  = blockIdx.x;              // b = (ug*4+gw)*48 + ks
    int ks = b % NKS;
    int gw = (b / NKS) & 3;
    int ug = b / (NKS * 4);
    const float* W = (gw == 0) ? Wi : (gw == 1) ? Wf : (gw == 2) ? Wc : Wo;
    int t  = threadIdx.x;
    int l  = t & 63;
    int ep = t >> 6;                  // element-pair 0..3
    int k   = ks * 32 + ((l >> 4) * 8) + ep * 2;
    int col = ug * 16 + (l & 15);
    float v0 = W[(size_t)k * HID_ + col];
    float v1 = W[(size_t)(k + 1) * HID_ + col];
    uint32_t pk = (uint32_t)f2b(v0) | ((uint32_t)f2b(v1) << 16);
    size_t dst = (((size_t)b) * 64 + l) * 8 + (size_t)ep * 2;
    *(uint32_t*)(whxp + dst) = pk;
}

// ---------- Per-timestep LSTM kernel ----------
// grid: 256 WGs, bid = bj*64 + ug  (ug = unit-group of 16 units, bj = batch-group of 16 rows)
// block: 256 threads = 4 waves; wave w computes gate w (M=16 batch, N=16 units, K=1536).
__global__ __launch_bounds__(256, 1) void lstm_step_k(
    const u16* __restrict__ whxp, const u16* __restrict__ embB,
    const int* __restrict__ x,
    const float* __restrict__ bi, const float* __restrict__ bf_,
    const float* __restrict__ bc, const float* __restrict__ bo,
    const u16* __restrict__ hprev, u16* __restrict__ hcur,
    float* __restrict__ cst, float* __restrict__ out, int t)
{
    __shared__ __align__(16) u16 Atile[16][ARS];   // 49,408 B: [batch row][k]  (k: 0..1023 h, 1024..1535 xe)
    __shared__ float gbuf[4][16][17];              // 4,352 B: [gate][row][unit]

    const int tid = threadIdx.x;
    const int w   = tid >> 6;         // gate index for this wave
    const int l   = tid & 63;
    const int ug  = blockIdx.x & 63;
    const int bj  = blockIdx.x >> 6;
    const int brow0 = bj * 16;

    // ---- B fragments: 48 x dwordx4 per lane, held in VGPRs for the whole step ----
    short8 bw[NKS];
    {
        const short8* bp = (const short8*)whxp + ((size_t)(ug * 4 + w) * NKS) * 64 + l;
        #pragma unroll
        for (int ks = 0; ks < NKS; ++ks) bw[ks] = bp[ks * 64];
    }

    // ---- Stage A-tile: h part (bf16 ping-pong buffer) ----
    if (t > 0) {
        const uint32_t* hsrc = (const uint32_t*)hprev;           // [64][512] u32 (2 bf16 each)
        #pragma unroll
        for (int it = 0; it < 8; ++it) {
            int i   = tid * 4 + it * 1024;
            int row = i >> 9;
            int k32 = i & 511;
            uint4 v = *(const uint4*)(hsrc + (size_t)(brow0 + row) * 512 + k32);
            *(uint4*)(&Atile[row][k32 * 2]) = v;
        }
    } else {
        uint4 z = make_uint4(0u, 0u, 0u, 0u);
        #pragma unroll
        for (int it = 0; it < 8; ++it) {
            int i = tid * 4 + it * 1024;
            *(uint4*)(&Atile[i >> 9][(i & 511) * 2]) = z;
        }
    }
    // ---- Stage A-tile: embedding part (gathered bf16 rows) ----
    {
        #pragma unroll
        for (int it = 0; it < 4; ++it) {
            int i   = tid * 4 + it * 1024;
            int row = i >> 8;
            int k32 = i & 255;
            int token = x[t * NB + brow0 + row];
            const uint32_t* esrc = (const uint32_t*)embB + (size_t)token * 256 + k32;
            uint4 v = *(const uint4*)esrc;
            *(uint4*)(&Atile[row][1024 + k32 * 2]) = v;
        }
    }
    __syncthreads();

    // ---- MFMA: acc = bias + A(16x1536) @ W(1536x16), two accumulators to break the chain ----
    const float* bptr = (w == 0) ? bi : (w == 1) ? bf_ : (w == 2) ? bc : bo;
    float bias = bptr[ug * 16 + (l & 15)];
    f32x4 acc0 = {bias, bias, bias, bias};
    f32x4 acc1 = {0.f, 0.f, 0.f, 0.f};

    const u16* arow = &Atile[l & 15][(l >> 4) * 8];
    #pragma unroll
    for (int ks = 0; ks < NKS; ks += 2) {
        short8 a0 = *(const short8*)(arow + ks * 32);
        short8 a1 = *(const short8*)(arow + ks * 32 + 32);
        acc0 = __builtin_amdgcn_mfma_f32_16x16x32_bf16(a0, bw[ks],     acc0, 0, 0, 0);
        acc1 = __builtin_amdgcn_mfma_f32_16x16x32_bf16(a1, bw[ks + 1], acc1, 0, 0, 0);
    }

    // ---- Publish gates to LDS (C layout: col = l&15, row = (l>>4)*4 + r) ----
    {
        int col = l & 15, rg = l >> 4;
        #pragma unroll
        for (int r = 0; r < 4; ++r)
            gbuf[w][rg * 4 + r][col] = acc0[r] + acc1[r];
    }
    __syncthreads();

    // ---- Elementwise LSTM update: one thread per (batch row, unit) ----
    {
        int row = tid >> 4, u = tid & 15;
        float gi = gbuf[0][row][u];
        float gf = gbuf[1][row][u];
        float gc = gbuf[2][row][u];
        float go = gbuf[3][row][u];
        size_t cidx = (size_t)(brow0 + row) * HID_ + (size_t)ug * 16 + u;
        float c_old = (t == 0) ? 0.f : cst[cidx];
        float fi = 1.f / (1.f + __expf(-gi));
        float ff = 1.f / (1.f + __expf(-gf));
        float fo = 1.f / (1.f + __expf(-go));
        float tc = 1.f - 2.f / (__expf(2.f * gc) + 1.f);     // tanh(gc)
        float cn = ff * c_old + fi * tc;
        float th = 1.f - 2.f / (__expf(2.f * cn) + 1.f);     // tanh(cn)
        float hn = fo * th;
        cst[cidx] = cn;
        out[(size_t)t * (NB * HID_) + cidx] = hn;
        hcur[cidx] = f2b(hn);
    }
}

extern "C" void kernel_launch(void* const* d_in, const int* in_sizes, int n_in,
                              void* d_out, int out_size, void* d_ws, size_t ws_size,
                              hipStream_t stream) {
    const int*   x   = (const int*)d_in[0];
    const float* emb = (const float*)d_in[1];
    const float* Wi  = (const float*)d_in[2];
    const float* bi  = (const float*)d_in[3];
    const float* Wf  = (const float*)d_in[4];
    const float* bf  = (const float*)d_in[5];
    const float* Wc  = (const float*)d_in[6];
    const float* bc  = (const float*)d_in[7];
    const float* Wo  = (const float*)d_in[8];
    const float* bo  = (const float*)d_in[9];
    float* out = (float*)d_out;

    // Workspace carve (total ~45.9 MB):
    char* ws = (char*)d_ws;
    u16*   whxp = (u16*)ws;                                    // 12,582,912 B packed weights (bf16)
    u16*   embB = (u16*)(ws + 12582912);                       // 32,768,000 B emb bf16
    u16*   hb   = (u16*)(ws + 12582912 + 32768000);            //    262,144 B h ping-pong (bf16)
    float* cst  = (float*)(ws + 12582912 + 32768000 + 262144); //    262,144 B c state (fp32)

    cvt_emb_k<<<8000, 256, 0, stream>>>(emb, embB);            // 32000*512/8/256 = 8000 exact
    pack_w_k<<<64 * 4 * NKS, 256, 0, stream>>>(Wi, Wf, Wc, Wo, whxp);

    for (int t = 0; t < L_SEQ; ++t) {
        u16* hpv = hb + (size_t)((t + 1) & 1) * (NB * HID_);
        u16* hcu = hb + (size_t)(t & 1) * (NB * HID_);
        lstm_step_k<<<256, 256, 0, stream>>>(whxp, embB, x, bi, bf, bc, bo,
                                             hpv, hcu, cst, out, t);
    }
}